// Round 6
// baseline (453.630 us; speedup 1.0000x reference)
//
#include <hip/hip_runtime.h>

#define NUM_CARDS 50000
#define NM1 49999
#define BATCH 1024
#define BPAD 50176             // padded cards (multiple of 1024); B rows NM1..BPAD-1 zero
#define NPAD (BPAD - NM1)      // 177 pad cards, each adds exp(0)=1 to S1
#define CARDS_PER_BLOCK 1024
#define NSLAB (CARDS_PER_BLOCK / 64)     // 16
#define GRIDY (BPAD / CARDS_PER_BLOCK)   // 49
#define KLEPS 1e-7f

typedef __attribute__((ext_vector_type(8))) short short8;   // 8 bf16
typedef __attribute__((ext_vector_type(4))) float f32x4;
typedef float f32x4u __attribute__((ext_vector_type(4), aligned(4)));  // adj rows 4B-aligned

// ws layout:
//   A bf16 : [0, 131072)        1024*64*2
//   B bf16 : [131072, 6553600)  50176*64*2, row j = l2norm(card j+1), pads zero
//   S1..S4 : [6553600, 6569984) 4 x 1024 f32
#define A_OFF  0
#define B_OFF  131072
#define S_OFF  6553600

__device__ inline unsigned short f2bf(float x) {
    unsigned int u = __float_as_uint(x);
    return (unsigned short)((u + 0x7FFFu + ((u >> 16) & 1u)) >> 16);  // RNE
}

// ---- prep: blocks [0,3136) normalize B (16 rows each); [3136,3392) MLP (4 rows each) ----
__global__ __launch_bounds__(256) void prep_kernel(
    const int* __restrict__ idx, const float* __restrict__ ce,
    const float* __restrict__ W1, const float* __restrict__ b1,
    const float* __restrict__ W2, const float* __restrict__ b2,
    unsigned short* __restrict__ Abf, unsigned short* __restrict__ Bbf,
    float* __restrict__ S)
{
    const int bid  = blockIdx.x;
    const int t    = threadIdx.x;
    const int lane = t & 63;
    const int wv   = t >> 6;

    if (bid < BPAD / 16) {
        #pragma unroll
        for (int i = 0; i < 4; ++i) {
            const int j = bid * 16 + wv * 4 + i;
            float v = (j < NM1) ? ce[(size_t)(j + 1) * 64 + lane] : 0.f;
            float ss = v * v;
            #pragma unroll
            for (int m = 1; m <= 32; m <<= 1) ss += __shfl_xor(ss, m, 64);
            float inv = rsqrtf(fmaxf(ss, 1e-12f));
            Bbf[(size_t)j * 64 + lane] = f2bf((j < NM1) ? v * inv : 0.f);
        }
        return;
    }

    if (bid == BPAD / 16) {                // zero S1..S4 (consumed by later kernels)
        #pragma unroll
        for (int p = 0; p < 16; ++p) S[t + p * 256] = 0.f;
    }

    // ---- MLP: 4 batch rows per block ----
    __shared__ float emb_s[4][64];
    __shared__ float hs[4][256];
    __shared__ int idx_s[4];
    const int i0 = (bid - BPAD / 16) * 4;
    if (t < 4) idx_s[t] = idx[i0 + t];
    __syncthreads();
    {
        int g = t >> 6, k = t & 63;        // 256 threads = 4x64 exactly
        emb_s[g][k] = ce[(size_t)idx_s[g] * 64 + k];
    }
    __syncthreads();
    {   // hidden layer: thread j computes h[g][j] for 4 rows
        const int j = t;
        float a4[4];
        float bj = b1[j];
        #pragma unroll
        for (int g = 0; g < 4; ++g) a4[g] = bj;
        #pragma unroll 8
        for (int k = 0; k < 64; ++k) {
            float w = W1[k * 256 + j];
            #pragma unroll
            for (int g = 0; g < 4; ++g) a4[g] = fmaf(emb_s[g][k], w, a4[g]);
        }
        #pragma unroll
        for (int g = 0; g < 4; ++g) hs[g][j] = fmaxf(a4[g], 0.f);
    }
    __syncthreads();
    {   // output layer: wave wv = row i0+wv, lane = dim d; then l2norm -> bf16
        const int d = lane;
        float o = b2[d];
        #pragma unroll 8
        for (int j = 0; j < 256; ++j)
            o = fmaf(hs[wv][j], W2[j * 64 + d], o);
        float ss = o * o;
        #pragma unroll
        for (int m = 1; m <= 32; m <<= 1) ss += __shfl_xor(ss, m, 64);
        o *= rsqrtf(fmaxf(ss, 1e-12f));
        Abf[(size_t)(i0 + wv) * 64 + d] = f2bf(o);
    }
}

// ================= fused sweep helpers =================
__device__ __forceinline__ f32x4 mfma2(const short8& a0, const short8& a1,
                                       const short8& b0, const short8& b1) {
    f32x4 z = {0.f, 0.f, 0.f, 0.f};
    return __builtin_amdgcn_mfma_f32_16x16x32_bf16(
               a1, b1, __builtin_amdgcn_mfma_f32_16x16x32_bf16(a0, b0, z, 0, 0, 0), 0, 0, 0);
}

template<bool TAIL>
__device__ __forceinline__ void load_slab(
    const unsigned short* __restrict__ Bbf, const float* const* rowp,
    int cb, int m, int quad,
    short8 b0[4], short8 b1[4], f32x4 y[4])
{
    #pragma unroll
    for (int g = 0; g < 4; ++g) {
        const unsigned short* bp = Bbf + (size_t)(cb + 16 * g + m) * 64;
        b0[g] = *(const short8*)(bp + quad * 8);
        b1[g] = *(const short8*)(bp + 32 + quad * 8);
    }
    if (!TAIL || cb + 63 < NM1) {
        #pragma unroll
        for (int r = 0; r < 4; ++r) {
            f32x4u v = *(const f32x4u*)(rowp[r] + cb + 4 * m);
            y[r][0] = v.x; y[r][1] = v.y; y[r][2] = v.z; y[r][3] = v.w;
        }
    } else {
        #pragma unroll
        for (int r = 0; r < 4; ++r) {
            #pragma unroll
            for (int k = 0; k < 4; ++k) {
                const int c = cb + 4 * m + k;
                float vv = -1.f;                 // sentinel: invalid card
                if (c < NM1) vv = rowp[r][c];
                y[r][k] = vv;
            }
        }
    }
}

template<bool TAIL>
__device__ __forceinline__ void compute_slab(
    const short8& a0, const short8& a1,
    const short8 b0[4], const short8 b1[4], const f32x4 y[4],
    float T, float* wbase, int m, int quad,
    float rs1[4], float rs2[4], float rs3[4], float rs4[4])
{
    f32x4 d[4];
    #pragma unroll
    for (int g = 0; g < 4; ++g) d[g] = mfma2(a0, a1, b0[g], b1[g]);

    #pragma unroll
    for (int g = 0; g < 4; ++g) {
        rs1[0] += __expf(T * d[g][0]);
        rs1[1] += __expf(T * d[g][1]);
        rs1[2] += __expf(T * d[g][2]);
        rs1[3] += __expf(T * d[g][3]);
        // wave-private LDS bounce: [card][row-quad] (stride 17 dwords)
        *(f32x4*)(wbase + (16 * g + m) * 17 + quad * 4) = d[g];
    }
    #pragma unroll
    for (int k = 0; k < 4; ++k) {
        f32x4 R = *(const f32x4*)(wbase + (4 * m + k) * 17 + quad * 4);
        #pragma unroll
        for (int r = 0; r < 4; ++r) {
            float yv = y[r][k];
            float t0 = fmaxf(yv, KLEPS);
            float tt = TAIL ? ((yv < 0.f) ? 0.f : t0) : t0;
            rs3[r] += tt * __logf(t0);     // 0 * log(eps) = 0 for invalid
            rs4[r] += tt;
            rs2[r] += tt * R[r];
        }
    }
}

template<bool TAIL>
__device__ __forceinline__ void sweep(
    const unsigned short* __restrict__ Bbf, const float* const* rowp,
    const short8& a0, const short8& a1,
    float T, float* wbase, int m, int quad, int cbase0,
    float rs1[4], float rs2[4], float rs3[4], float rs4[4])
{
    short8 pb0[4], pb1[4]; f32x4 py[4];    // ping
    short8 qb0[4], qb1[4]; f32x4 qy[4];    // pong
    load_slab<TAIL>(Bbf, rowp, cbase0, m, quad, pb0, pb1, py);
    #pragma unroll 1
    for (int sp = 0; sp < NSLAB / 2; ++sp) {
        load_slab<TAIL>(Bbf, rowp, cbase0 + (2 * sp + 1) * 64, m, quad, qb0, qb1, qy);
        compute_slab<TAIL>(a0, a1, pb0, pb1, py, T, wbase, m, quad, rs1, rs2, rs3, rs4);
        if (sp < NSLAB / 2 - 1)
            load_slab<TAIL>(Bbf, rowp, cbase0 + (2 * sp + 2) * 64, m, quad, pb0, pb1, py);
        compute_slab<TAIL>(a0, a1, qb0, qb1, qy, T, wbase, m, quad, rs1, rs2, rs3, rs4);
    }
}

// ---- fused streaming sweep: S1=Σexp(T·s), S2=Σ yt·s, S3=Σ yt·log yt, S4=Σ yt ----
__global__ __launch_bounds__(256, 3) void fused_kernel(
    const unsigned short* __restrict__ Abf,
    const unsigned short* __restrict__ Bbf,
    const float* __restrict__ adj,
    const float* __restrict__ temp_p,
    float* __restrict__ S)
{
    __shared__ float sc[4][64 * 17];       // per-wave score bounce, 68B card stride
    float* S1 = S; float* S2 = S + 1024; float* S3 = S + 2048; float* S4 = S + 3072;

    const int lane = threadIdx.x & 63;
    const int wv   = threadIdx.x >> 6;
    const int m    = lane & 15;
    const int quad = lane >> 4;
    const int r0   = blockIdx.x * 64 + wv * 16;
    const float T  = *temp_p;

    const size_t arow = (size_t)(r0 + m) * 64;
    const short8 a0 = *(const short8*)(Abf + arow + quad * 8);
    const short8 a1 = *(const short8*)(Abf + arow + 32 + quad * 8);

    const float* rowp[4];
    #pragma unroll
    for (int r = 0; r < 4; ++r) rowp[r] = adj + (size_t)(r0 + quad * 4 + r) * NM1;

    float rs1[4] = {0,0,0,0}, rs2[4] = {0,0,0,0};
    float rs3[4] = {0,0,0,0}, rs4[4] = {0,0,0,0};

    float* wbase = sc[wv];
    const int cbase0 = blockIdx.y * CARDS_PER_BLOCK;

    if (cbase0 + CARDS_PER_BLOCK <= NM1)
        sweep<false>(Bbf, rowp, a0, a1, T, wbase, m, quad, cbase0, rs1, rs2, rs3, rs4);
    else
        sweep<true>(Bbf, rowp, a0, a1, T, wbase, m, quad, cbase0, rs1, rs2, rs3, rs4);

    #pragma unroll
    for (int r = 0; r < 4; ++r) {
        float v1 = rs1[r], v2 = rs2[r], v3 = rs3[r], v4 = rs4[r];
        #pragma unroll
        for (int s = 1; s <= 8; s <<= 1) {
            v1 += __shfl_xor(v1, s, 64);
            v2 += __shfl_xor(v2, s, 64);
            v3 += __shfl_xor(v3, s, 64);
            v4 += __shfl_xor(v4, s, 64);
        }
        if (m == 0) {
            const int row = r0 + quad * 4 + r;
            atomicAdd(&S1[row], v1);
            atomicAdd(&S2[row], v2);
            atomicAdd(&S3[row], v3);
            atomicAdd(&S4[row], v4);
        }
    }
}

// ---- finalize: loss = Σ_r [S3 - T·S2 + log(S1-NPAD)·S4] / (B ln2) + T²/100 ----
__global__ __launch_bounds__(256) void fin_kernel(
    const float* __restrict__ S, const float* __restrict__ temp_p,
    float* __restrict__ out)
{
    const float* S1 = S; const float* S2 = S + 1024;
    const float* S3 = S + 2048; const float* S4 = S + 3072;
    const float T = *temp_p;
    const int t = threadIdx.x;
    float local = 0.f;
    #pragma unroll
    for (int p = 0; p < 4; ++p) {
        const int row = t + p * 256;
        float lse = __logf(S1[row] - (float)NPAD);
        local += S3[row] - T * S2[row] + lse * S4[row];
    }
    #pragma unroll
    for (int s = 1; s <= 32; s <<= 1) local += __shfl_xor(local, s, 64);
    __shared__ float wacc[4];
    if ((t & 63) == 0) wacc[t >> 6] = local;
    __syncthreads();
    if (t == 0)
        out[0] = (wacc[0] + wacc[1] + wacc[2] + wacc[3])
                 * (1.0f / (BATCH * 0.69314718055994531f))
               + T * T * 0.01f;
}

extern "C" void kernel_launch(void* const* d_in, const int* in_sizes, int n_in,
                              void* d_out, int out_size, void* d_ws, size_t ws_size,
                              hipStream_t stream) {
    const int*   single_card = (const int*)d_in[0];
    const float* adj         = (const float*)d_in[1];
    const float* ce          = (const float*)d_in[2];
    const float* W1          = (const float*)d_in[3];
    const float* b1          = (const float*)d_in[4];
    const float* W2          = (const float*)d_in[5];
    const float* b2          = (const float*)d_in[6];
    const float* temp        = (const float*)d_in[7];

    char* ws = (char*)d_ws;
    unsigned short* Abf = (unsigned short*)(ws + A_OFF);
    unsigned short* Bbf = (unsigned short*)(ws + B_OFF);
    float* S            = (float*)(ws + S_OFF);

    prep_kernel<<<BPAD / 16 + BATCH / 4, 256, 0, stream>>>(single_card, ce, W1, b1, W2, b2,
                                                           Abf, Bbf, S);
    fused_kernel<<<dim3(16, GRIDY), 256, 0, stream>>>(Abf, Bbf, adj, temp, S);
    fin_kernel<<<1, 256, 0, stream>>>(S, temp, (float*)d_out);
}